// Round 1
// baseline (381.713 us; speedup 1.0000x reference)
//
#include <hip/hip_runtime.h>

typedef unsigned short u16;
typedef unsigned int   u32;
typedef __attribute__((ext_vector_type(8))) __bf16 bf16x8;
typedef __attribute__((ext_vector_type(4))) float  f32x4;
typedef __attribute__((ext_vector_type(4))) u16    u16x4;

#define DEV __device__ __forceinline__

DEV u16 f2b(float f){ union{float f;u32 u;}a; a.f=f; u32 r=a.u + 0x7FFFu + ((a.u>>16)&1u); return (u16)(r>>16); }
DEV float b2f(u16 h){ union{u32 u;float f;}a; a.u=((u32)h)<<16; return a.f; }

typedef __attribute__((address_space(1))) void* gp1;
typedef __attribute__((address_space(3))) void* lp3;
DEV void gl16(const void* g, void* l){
  __builtin_amdgcn_global_load_lds((gp1)g, (lp3)l, 16, 0, 0);
}

// ---------------------------------------------------------------------------
// prep: bf16 conversions, transposed small operands, D11^T/lam, invLam
// ---------------------------------------------------------------------------
__global__ __launch_bounds__(256) void k_prep(
    const float* __restrict__ C1, const float* __restrict__ D11,
    const float* __restrict__ D12, const float* __restrict__ Lam,
    const float* __restrict__ E,  const float* __restrict__ F,
    const float* __restrict__ B1, const float* __restrict__ B2,
    const float* __restrict__ C2, const float* __restrict__ D21,
    u16* Ebf, u16* Y0, u16* Z0, u16* McatT, u16* Qt, u16* Rt,
    float* D11Ts, float* invLam)
{
  int idx = blockIdx.x * 256 + threadIdx.x;
  if (idx < 262144) {                       // Ebf, Y0 = 2I-E, Z0 = Y0^T
    int i = idx >> 9, j = idx & 511;
    float e = E[idx];
    Ebf[idx] = f2b(e);
    float dij = (i == j) ? 2.f : 0.f;
    Y0[idx] = f2b(dij - e);
    Z0[idx] = f2b(dij - E[j * 512 + i]);
    return;
  }
  idx -= 262144;
  if (idx < 458752) {                       // McatT (896x512) = [F B1 B2]^T
    int j = idx >> 9, c = idx & 511;
    float v = (j < 512) ? F[c * 512 + j]
              : (j < 768 ? B1[c * 256 + (j - 512)] : B2[c * 128 + (j - 768)]);
    McatT[idx] = f2b(v);
    return;
  }
  idx -= 458752;
  if (idx < 114688) {                       // Qt rows 512..639 (y part)
    int j = idx / 896, k = idx - j * 896;
    float v = (k < 512) ? C2[j * 512 + k]
              : (k < 768 ? D21[j * 256 + (k - 512)] : 0.f);
    Qt[(size_t)(512 + j) * 896 + k] = f2b(v);
    return;
  }
  idx -= 114688;
  if (idx < 229376) {                       // Rt (256x896): [C1 | 0 | D12]
    int n = idx / 896, k = idx - n * 896;
    float v = (k < 512) ? C1[n * 512 + k]
              : (k < 768 ? 0.f : D12[n * 128 + (k - 768)]);
    Rt[idx] = f2b(v);
    return;
  }
  idx -= 229376;
  if (idx < 65536) {                        // D11Ts[j][n] = D11[n][j]/lam[n]
    int j = idx >> 8, n = idx & 255;
    D11Ts[idx] = D11[n * 256 + j] / Lam[n * 256 + n];
    return;
  }
  idx -= 65536;
  if (idx < 256) invLam[idx] = 1.f / Lam[idx * 256 + idx];
}

// ---------------------------------------------------------------------------
// convert P = [x | (w later) | u] to bf16, row length 896
// ---------------------------------------------------------------------------
__global__ __launch_bounds__(256) void k_convP(
    const float* __restrict__ x, const float* __restrict__ u, u16* __restrict__ P)
{
  int idx = blockIdx.x * 256 + threadIdx.x;
  if (idx >= 8192 * 160) return;
  int b = idx / 160, t = idx - b * 160;
  f32x4 s; u16* dst;
  if (t < 128) { s = *(const f32x4*)(x + (size_t)b * 512 + t * 4); dst = P + (size_t)b * 896 + t * 4; }
  else         { s = *(const f32x4*)(u + (size_t)b * 128 + (t - 128) * 4); dst = P + (size_t)b * 896 + 768 + (t - 128) * 4; }
  u16x4 o; o.x = f2b(s.x); o.y = f2b(s.y); o.z = f2b(s.z); o.w = f2b(s.w);
  *(u16x4*)dst = o;
}

// ---------------------------------------------------------------------------
// generic NT bf16 MFMA GEMM: out[i][j] = sum_c A[i][c]*B[j][c]
// 128x128 tile, BK=32, 256 threads (2x2 waves, 64x64 per wave)
// ---------------------------------------------------------------------------
struct GemmArgs {
  const u16* A; const u16* B; int K;
  float* outF;                 // EPI 0 (base2, ld=256)
  u16* outB; int ldB;          // primary bf16
  u16* outBT;                  // transposed bf16 (ld=512)
  const u16* Yprev;            // EPI 4
  const float* bv; const float* iLam;
  float* dxOut; float* yOut;   // EPI 1
};

template<int EPI>
__global__ __launch_bounds__(256) void gemm_nt(GemmArgs g)
{
  __shared__ __align__(16) u16 As[128 * 32];
  __shared__ __align__(16) u16 Bs[128 * 32];
  const int tid = threadIdx.x;
  const int l = tid & 63, w = tid >> 6;
  const int bm = blockIdx.y, bn = blockIdx.x;
  const int K = g.K;
  const size_t rowb = (size_t)K * 2;
  const char* Ab = (const char*)g.A + (size_t)bm * 128 * rowb;
  const char* Bb = (const char*)g.B + (size_t)bn * 128 * rowb;
  const int o1 = w * 1024 + l * 16, o2 = o1 + 4096;
  const int r1 = o1 >> 6, c1 = o1 & 63, r2 = o2 >> 6, c2 = o2 & 63;
  char* AsB = (char*)As; char* BsB = (char*)Bs;
  const int wm = w >> 1, wn = w & 1;
  const int lr = l & 15, lk = l >> 4;

  f32x4 acc[4][4];
  const f32x4 zz = {0.f, 0.f, 0.f, 0.f};
  #pragma unroll
  for (int i = 0; i < 4; i++)
    #pragma unroll
    for (int j = 0; j < 4; j++) acc[i][j] = zz;

  for (int k0 = 0; k0 < K; k0 += 32) {
    gl16(Ab + (size_t)r1 * rowb + k0 * 2 + c1, AsB + o1);
    gl16(Ab + (size_t)r2 * rowb + k0 * 2 + c2, AsB + o2);
    gl16(Bb + (size_t)r1 * rowb + k0 * 2 + c1, BsB + o1);
    gl16(Bb + (size_t)r2 * rowb + k0 * 2 + c2, BsB + o2);
    __syncthreads();
    bf16x8 af[4], bfv[4];
    #pragma unroll
    for (int mi = 0; mi < 4; mi++)
      af[mi] = *(const bf16x8*)(AsB + (wm * 64 + mi * 16 + lr) * 64 + lk * 16);
    #pragma unroll
    for (int ni = 0; ni < 4; ni++)
      bfv[ni] = *(const bf16x8*)(BsB + (wn * 64 + ni * 16 + lr) * 64 + lk * 16);
    #pragma unroll
    for (int mi = 0; mi < 4; mi++)
      #pragma unroll
      for (int ni = 0; ni < 4; ni++)
        acc[mi][ni] = __builtin_amdgcn_mfma_f32_16x16x32_bf16(af[mi], bfv[ni], acc[mi][ni], 0, 0, 0);
    __syncthreads();
  }

  #pragma unroll
  for (int mi = 0; mi < 4; mi++) {
    #pragma unroll
    for (int ni = 0; ni < 4; ni++) {
      const int row0 = bm * 128 + wm * 64 + mi * 16 + lk * 4;
      const int col  = bn * 128 + wn * 64 + ni * 16 + lr;
      if (EPI == 0) {
        const float bvc = g.bv[col], il = g.iLam[col];
        #pragma unroll
        for (int r = 0; r < 4; r++)
          g.outF[(size_t)(row0 + r) * 256 + col] = (acc[mi][ni][r] + bvc) * il;
      } else if (EPI == 1) {
        #pragma unroll
        for (int r = 0; r < 4; r++) {
          float v = acc[mi][ni][r];
          if (col < 512) g.dxOut[(size_t)(row0 + r) * 512 + col] = v;
          else           g.yOut[(size_t)(row0 + r) * 128 + (col - 512)] = v;
        }
      } else if (EPI == 2) {
        #pragma unroll
        for (int r = 0; r < 4; r++)
          g.outB[(size_t)(row0 + r) * g.ldB + col] = f2b(acc[mi][ni][r]);
      } else if (EPI == 3) {
        #pragma unroll
        for (int r = 0; r < 4; r++)
          g.outBT[(size_t)col * 512 + (row0 + r)] = f2b(acc[mi][ni][r]);
      } else if (EPI == 4) {
        #pragma unroll
        for (int r = 0; r < 4; r++) {
          int row = row0 + r;
          float d = 2.f * b2f(g.Yprev[row * 512 + col]) - acc[mi][ni][r];
          u16 hb = f2b(d);
          g.outB[row * 512 + col] = hb;
          if (g.outBT) g.outBT[col * 512 + row] = hb;
        }
      }
    }
  }
}

// ---------------------------------------------------------------------------
// sequential tanh recurrence (right-looking rank-1 updates)
// 256 blocks x 256 thr; wave = 8 rows x 8 chunks of 32 n; acc in regs
// ---------------------------------------------------------------------------
__global__ __launch_bounds__(256) void k_solve(
    const float* __restrict__ base2, const float* __restrict__ D11Ts,
    u16* __restrict__ P)
{
  __shared__ __align__(16) char Dlds[32 * 1024];   // 32 rows x 256 f32, swizzled
  const int tid = threadIdx.x, l = tid & 63, w = tid >> 6;
  const int rr = l & 7, c = l >> 3;
  const int row = blockIdx.x * 32 + w * 8 + rr;

  float bvv[32], acc[32];
  const float* brow = base2 + (size_t)row * 256 + c * 32;
  #pragma unroll
  for (int j = 0; j < 8; j++) {
    f32x4 t = *(const f32x4*)(brow + j * 4);
    bvv[j*4+0] = t.x; bvv[j*4+1] = t.y; bvv[j*4+2] = t.z; bvv[j*4+3] = t.w;
    acc[j*4+0] = 0.f; acc[j*4+1] = 0.f; acc[j*4+2] = 0.f; acc[j*4+3] = 0.f;
  }
  int swz[8];
  #pragma unroll
  for (int j = 0; j < 8; j++) {
    int lin = c * 128 + j * 16;
    swz[j] = lin ^ ((lin >> 3) & 0x70);
  }
  const char* Dg = (const char*)D11Ts;
  const int d = l * 16;
  const int srcoff = d ^ ((d >> 3) & 0x70);      // pre-swizzled source (involution)

  for (int kt = 0; kt < 8; kt++) {
    #pragma unroll
    for (int r = 0; r < 8; r++)
      gl16(Dg + (size_t)(kt * 32 + w * 8 + r) * 1024 + srcoff,
           Dlds + w * 8192 + r * 1024 + d);
    __syncthreads();
    #pragma unroll
    for (int k2 = 0; k2 < 32; k2++) {
      const int k = kt * 32 + k2;
      float v = bvv[k2] + acc[k2];               // valid on owner chunk (c==kt)
      float e = __expf(2.f * v);
      float wv0 = 1.f - __fdividef(2.f, e + 1.f);
      float wv = __shfl(wv0, kt * 8 + rr, 64);
      if (c == kt) P[(size_t)row * 896 + 512 + k] = f2b(wv);
      #pragma unroll
      for (int j = 0; j < 8; j++) {
        f32x4 dv = *(const f32x4*)(Dlds + k2 * 1024 + swz[j]);
        acc[j*4+0] += wv * dv.x; acc[j*4+1] += wv * dv.y;
        acc[j*4+2] += wv * dv.z; acc[j*4+3] += wv * dv.w;
      }
    }
    __syncthreads();
  }
}

// ---------------------------------------------------------------------------
extern "C" void kernel_launch(void* const* d_in, const int* in_sizes, int n_in,
                              void* d_out, int out_size, void* d_ws, size_t ws_size,
                              hipStream_t stream)
{
  const float* x   = (const float*)d_in[0];
  const float* u   = (const float*)d_in[1];
  const float* C1  = (const float*)d_in[2];
  const float* D11 = (const float*)d_in[3];
  const float* D12 = (const float*)d_in[4];
  const float* Lam = (const float*)d_in[5];
  const float* bv  = (const float*)d_in[6];
  const float* E   = (const float*)d_in[7];
  const float* F   = (const float*)d_in[8];
  const float* B1  = (const float*)d_in[9];
  const float* B2  = (const float*)d_in[10];
  const float* C2  = (const float*)d_in[11];
  const float* D21 = (const float*)d_in[12];

  char* ws = (char*)d_ws;
  u16*   P     = (u16*)(ws);                  // 8192x896 bf16  = 14,680,064
  u16*   Qt    = (u16*)(ws + 14680064);       // 640x896 bf16   =  1,146,880
  u16*   Rt    = (u16*)(ws + 15826944);       // 256x896 bf16   =    458,752
  float* base2 = (float*)(ws + 16285696);     // 8192x256 f32   =  8,388,608
  float* D11Ts = (float*)(ws + 24674304);     // 256x256 f32    =    262,144
  u16*   Ebf   = (u16*)(ws + 24936448);
  u16*   Y0    = (u16*)(ws + 25460736);
  u16*   Z0    = (u16*)(ws + 25985024);
  u16*   T0T   = (u16*)(ws + 26509312);
  u16*   Y1    = (u16*)(ws + 27033600);
  u16*   Z1    = (u16*)(ws + 27557888);
  u16*   T1T   = (u16*)(ws + 28082176);
  u16*   Y2    = (u16*)(ws + 28606464);
  u16*   McatT = (u16*)(ws + 29130752);       // 896x512 bf16   =    917,504
  float* invLam= (float*)(ws + 30048256);     // 256 f32

  float* dxOut = (float*)d_out;
  float* yOut  = dxOut + (size_t)8192 * 512;

  k_prep<<<4417, 256, 0, stream>>>(C1, D11, D12, Lam, E, F, B1, B2, C2, D21,
                                   Ebf, Y0, Z0, McatT, Qt, Rt, D11Ts, invLam);
  k_convP<<<5120, 256, 0, stream>>>(x, u, P);

  GemmArgs a{}; a.A = Ebf; a.B = Z0; a.K = 512; a.outBT = T0T;
  gemm_nt<3><<<dim3(4, 4), 256, 0, stream>>>(a);             // T0^T = (E@Y0)^T

  GemmArgs b{}; b.A = Y0; b.B = T0T; b.K = 512; b.outB = Y1; b.ldB = 512;
  b.outBT = Z1; b.Yprev = Y0;
  gemm_nt<4><<<dim3(4, 4), 256, 0, stream>>>(b);             // Y1 = 2Y0 - Y0@T0 (+Z1)

  GemmArgs cc{}; cc.A = Ebf; cc.B = Z1; cc.K = 512; cc.outBT = T1T;
  gemm_nt<3><<<dim3(4, 4), 256, 0, stream>>>(cc);            // T1^T

  GemmArgs dd{}; dd.A = Y1; dd.B = T1T; dd.K = 512; dd.outB = Y2; dd.ldB = 512;
  dd.Yprev = Y1; dd.outBT = nullptr;
  gemm_nt<4><<<dim3(4, 4), 256, 0, stream>>>(dd);            // Y2 = 2Y1 - Y1@T1

  GemmArgs qq{}; qq.A = Y2; qq.B = McatT; qq.K = 512; qq.outB = Qt; qq.ldB = 896;
  gemm_nt<2><<<dim3(7, 4), 256, 0, stream>>>(qq);            // Qt[0:512] = Einv@[F B1 B2]

  GemmArgs bb{}; bb.A = P; bb.B = Rt; bb.K = 896; bb.outF = base2;
  bb.bv = bv; bb.iLam = invLam;
  gemm_nt<0><<<dim3(2, 64), 256, 0, stream>>>(bb);           // base2 = (x@C1^T+u@D12^T+bv)/lam

  k_solve<<<256, 256, 0, stream>>>(base2, D11Ts, P);         // w -> P[:,512:768] (bf16)

  GemmArgs ff{}; ff.A = P; ff.B = Qt; ff.K = 896; ff.dxOut = dxOut; ff.yOut = yOut;
  gemm_nt<1><<<dim3(5, 64), 256, 0, stream>>>(ff);           // [dx | y]
  (void)in_sizes; (void)n_in; (void)out_size; (void)ws_size;
}

// Round 2
// 171.115 us; speedup vs baseline: 2.2307x; 2.2307x over previous
//
#include <hip/hip_runtime.h>

typedef unsigned short u16;
typedef unsigned int   u32;
typedef __attribute__((ext_vector_type(8))) __bf16 bf16x8;
typedef __attribute__((ext_vector_type(4))) float  f32x4;
typedef __attribute__((ext_vector_type(4))) u16    u16x4;

#define DEV __device__ __forceinline__

DEV u16 f2b(float f){ union{float f;u32 u;}a; a.f=f; u32 r=a.u + 0x7FFFu + ((a.u>>16)&1u); return (u16)(r>>16); }
DEV float b2f(u16 h){ union{u32 u;float f;}a; a.u=((u32)h)<<16; return a.f; }

typedef __attribute__((address_space(1))) void* gp1;
typedef __attribute__((address_space(3))) void* lp3;
DEV void gl16(const void* g, void* l){
  __builtin_amdgcn_global_load_lds((gp1)g, (lp3)l, 16, 0, 0);
}

// ---------------------------------------------------------------------------
// prep: bf16 conversions, transposed small operands, D11^T/lam, invLam
// ---------------------------------------------------------------------------
__global__ __launch_bounds__(256) void k_prep(
    const float* __restrict__ C1, const float* __restrict__ D11,
    const float* __restrict__ D12, const float* __restrict__ Lam,
    const float* __restrict__ E,  const float* __restrict__ F,
    const float* __restrict__ B1, const float* __restrict__ B2,
    const float* __restrict__ C2, const float* __restrict__ D21,
    u16* Ebf, u16* Y0, u16* Z0, u16* McatT, u16* Qt, u16* Rt,
    float* D11Ts, float* invLam)
{
  int idx = blockIdx.x * 256 + threadIdx.x;
  if (idx < 262144) {                       // Ebf, Y0 = 2I-E, Z0 = Y0^T
    int i = idx >> 9, j = idx & 511;
    float e = E[idx];
    Ebf[idx] = f2b(e);
    float dij = (i == j) ? 2.f : 0.f;
    Y0[idx] = f2b(dij - e);
    Z0[idx] = f2b(dij - E[j * 512 + i]);
    return;
  }
  idx -= 262144;
  if (idx < 458752) {                       // McatT (896x512) = [F B1 B2]^T
    int j = idx >> 9, c = idx & 511;
    float v = (j < 512) ? F[c * 512 + j]
              : (j < 768 ? B1[c * 256 + (j - 512)] : B2[c * 128 + (j - 768)]);
    McatT[idx] = f2b(v);
    return;
  }
  idx -= 458752;
  if (idx < 114688) {                       // Qt rows 512..639 (y part)
    int j = idx / 896, k = idx - j * 896;
    float v = (k < 512) ? C2[j * 512 + k]
              : (k < 768 ? D21[j * 256 + (k - 512)] : 0.f);
    Qt[(size_t)(512 + j) * 896 + k] = f2b(v);
    return;
  }
  idx -= 114688;
  if (idx < 229376) {                       // Rt (256x896): [C1 | 0 | D12]
    int n = idx / 896, k = idx - n * 896;
    float v = (k < 512) ? C1[n * 512 + k]
              : (k < 768 ? 0.f : D12[n * 128 + (k - 768)]);
    Rt[idx] = f2b(v);
    return;
  }
  idx -= 229376;
  if (idx < 65536) {                        // D11Ts[j][n] = D11[n][j]/lam[n]
    int j = idx >> 8, n = idx & 255;
    D11Ts[idx] = D11[n * 256 + j] / Lam[n * 256 + n];
    return;
  }
  idx -= 65536;
  if (idx < 256) invLam[idx] = 1.f / Lam[idx * 256 + idx];
}

// ---------------------------------------------------------------------------
// convert P = [x | (w later) | u] to bf16, row length 896
// ---------------------------------------------------------------------------
__global__ __launch_bounds__(256) void k_convP(
    const float* __restrict__ x, const float* __restrict__ u, u16* __restrict__ P)
{
  int idx = blockIdx.x * 256 + threadIdx.x;
  if (idx >= 8192 * 160) return;
  int b = idx / 160, t = idx - b * 160;
  f32x4 s; u16* dst;
  if (t < 128) { s = *(const f32x4*)(x + (size_t)b * 512 + t * 4); dst = P + (size_t)b * 896 + t * 4; }
  else         { s = *(const f32x4*)(u + (size_t)b * 128 + (t - 128) * 4); dst = P + (size_t)b * 896 + 768 + (t - 128) * 4; }
  u16x4 o; o.x = f2b(s.x); o.y = f2b(s.y); o.z = f2b(s.z); o.w = f2b(s.w);
  *(u16x4*)dst = o;
}

// ---------------------------------------------------------------------------
// generic NT bf16 MFMA GEMM: out[i][j] = sum_c A[i][c]*B[j][c]
// 128x128 tile, BK=32, 256 threads (2x2 waves, 64x64 per wave)
// ---------------------------------------------------------------------------
struct GemmArgs {
  const u16* A; const u16* B; int K;
  float* outF;                 // EPI 0 (base2, ld=256)
  u16* outB; int ldB;          // primary bf16
  u16* outBT;                  // transposed bf16 (ld=512)
  const u16* Yprev;            // EPI 4
  const float* bv; const float* iLam;
  float* dxOut; float* yOut;   // EPI 1
};

template<int EPI>
__global__ __launch_bounds__(256) void gemm_nt(GemmArgs g)
{
  __shared__ __align__(16) u16 As[128 * 32];
  __shared__ __align__(16) u16 Bs[128 * 32];
  const int tid = threadIdx.x;
  const int l = tid & 63, w = tid >> 6;
  const int bm = blockIdx.y, bn = blockIdx.x;
  const int K = g.K;
  const size_t rowb = (size_t)K * 2;
  const char* Ab = (const char*)g.A + (size_t)bm * 128 * rowb;
  const char* Bb = (const char*)g.B + (size_t)bn * 128 * rowb;
  const int o1 = w * 1024 + l * 16, o2 = o1 + 4096;
  const int r1 = o1 >> 6, c1 = o1 & 63, r2 = o2 >> 6, c2 = o2 & 63;
  char* AsB = (char*)As; char* BsB = (char*)Bs;
  const int wm = w >> 1, wn = w & 1;
  const int lr = l & 15, lk = l >> 4;

  f32x4 acc[4][4];
  const f32x4 zz = {0.f, 0.f, 0.f, 0.f};
  #pragma unroll
  for (int i = 0; i < 4; i++)
    #pragma unroll
    for (int j = 0; j < 4; j++) acc[i][j] = zz;

  for (int k0 = 0; k0 < K; k0 += 32) {
    gl16(Ab + (size_t)r1 * rowb + k0 * 2 + c1, AsB + o1);
    gl16(Ab + (size_t)r2 * rowb + k0 * 2 + c2, AsB + o2);
    gl16(Bb + (size_t)r1 * rowb + k0 * 2 + c1, BsB + o1);
    gl16(Bb + (size_t)r2 * rowb + k0 * 2 + c2, BsB + o2);
    __syncthreads();
    bf16x8 af[4], bfv[4];
    #pragma unroll
    for (int mi = 0; mi < 4; mi++)
      af[mi] = *(const bf16x8*)(AsB + (wm * 64 + mi * 16 + lr) * 64 + lk * 16);
    #pragma unroll
    for (int ni = 0; ni < 4; ni++)
      bfv[ni] = *(const bf16x8*)(BsB + (wn * 64 + ni * 16 + lr) * 64 + lk * 16);
    #pragma unroll
    for (int mi = 0; mi < 4; mi++)
      #pragma unroll
      for (int ni = 0; ni < 4; ni++)
        acc[mi][ni] = __builtin_amdgcn_mfma_f32_16x16x32_bf16(af[mi], bfv[ni], acc[mi][ni], 0, 0, 0);
    __syncthreads();
  }

  #pragma unroll
  for (int mi = 0; mi < 4; mi++) {
    #pragma unroll
    for (int ni = 0; ni < 4; ni++) {
      const int row0 = bm * 128 + wm * 64 + mi * 16 + lk * 4;
      const int col  = bn * 128 + wn * 64 + ni * 16 + lr;
      if (EPI == 0) {
        const float bvc = g.bv[col], il = g.iLam[col];
        #pragma unroll
        for (int r = 0; r < 4; r++)
          g.outF[(size_t)(row0 + r) * 256 + col] = (acc[mi][ni][r] + bvc) * il;
      } else if (EPI == 1) {
        #pragma unroll
        for (int r = 0; r < 4; r++) {
          float v = acc[mi][ni][r];
          if (col < 512) g.dxOut[(size_t)(row0 + r) * 512 + col] = v;
          else           g.yOut[(size_t)(row0 + r) * 128 + (col - 512)] = v;
        }
      } else if (EPI == 2) {
        #pragma unroll
        for (int r = 0; r < 4; r++)
          g.outB[(size_t)(row0 + r) * g.ldB + col] = f2b(acc[mi][ni][r]);
      } else if (EPI == 3) {
        #pragma unroll
        for (int r = 0; r < 4; r++)
          g.outBT[(size_t)col * 512 + (row0 + r)] = f2b(acc[mi][ni][r]);
      } else if (EPI == 4) {
        #pragma unroll
        for (int r = 0; r < 4; r++) {
          int row = row0 + r;
          float d = 2.f * b2f(g.Yprev[row * 512 + col]) - acc[mi][ni][r];
          u16 hb = f2b(d);
          g.outB[row * 512 + col] = hb;
          if (g.outBT) g.outBT[col * 512 + row] = hb;
        }
      }
    }
  }
}

// ---------------------------------------------------------------------------
// sequential tanh recurrence (right-looking rank-1 updates)
// 512 blocks x 256 thr; 16 rows/block, 4 rows/wave; 16 lanes x 16 cols each
// acc[16] persistent (includes base); D tile (32x256 f32) staged in LDS
// ---------------------------------------------------------------------------
__global__ __launch_bounds__(256) void k_solve(
    const float* __restrict__ base2, const float* __restrict__ D11Ts,
    u16* __restrict__ P)
{
  __shared__ __align__(16) char Dlds[32 * 1024];   // 32 rows x 256 f32, linear
  const int tid = threadIdx.x, l = tid & 63, w = tid >> 6;
  const int r = l & 3, c = l >> 2;                 // row-in-wave, col-chunk
  const int row = blockIdx.x * 16 + w * 4 + r;

  float acc[16];
  const float* brow = base2 + (size_t)row * 256 + c * 16;
  #pragma unroll
  for (int j = 0; j < 4; j++) {
    f32x4 t = *(const f32x4*)(brow + j * 4);
    acc[j*4+0] = t.x; acc[j*4+1] = t.y; acc[j*4+2] = t.z; acc[j*4+3] = t.w;
  }
  const char* Dg = (const char*)D11Ts;
  const int d16 = tid * 16;

  for (int kt = 0; kt < 8; kt++) {
    #pragma unroll
    for (int s = 0; s < 8; s++)
      gl16(Dg + (size_t)kt * 32768 + s * 4096 + d16, Dlds + s * 4096 + d16);
    __syncthreads();
    for (int k2 = 0; k2 < 32; k2++) {
      const int k = kt * 32 + k2;
      const int own = k >> 4;                      // owning col-chunk
      float v = acc[k2 & 15];                      // meaningful on owner lanes
      float e = __expf(2.f * v);
      float wv0 = 1.f - __fdividef(2.f, e + 1.f);
      float wv = __shfl(wv0, own * 4 + r, 64);
      if (c == own) P[(size_t)row * 896 + 512 + k] = f2b(wv);
      #pragma unroll
      for (int j = 0; j < 4; j++) {
        f32x4 dv = *(const f32x4*)(Dlds + k2 * 1024 + c * 64 + j * 16);
        acc[j*4+0] += wv * dv.x; acc[j*4+1] += wv * dv.y;
        acc[j*4+2] += wv * dv.z; acc[j*4+3] += wv * dv.w;
      }
    }
    __syncthreads();
  }
}

// ---------------------------------------------------------------------------
extern "C" void kernel_launch(void* const* d_in, const int* in_sizes, int n_in,
                              void* d_out, int out_size, void* d_ws, size_t ws_size,
                              hipStream_t stream)
{
  const float* x   = (const float*)d_in[0];
  const float* u   = (const float*)d_in[1];
  const float* C1  = (const float*)d_in[2];
  const float* D11 = (const float*)d_in[3];
  const float* D12 = (const float*)d_in[4];
  const float* Lam = (const float*)d_in[5];
  const float* bv  = (const float*)d_in[6];
  const float* E   = (const float*)d_in[7];
  const float* F   = (const float*)d_in[8];
  const float* B1  = (const float*)d_in[9];
  const float* B2  = (const float*)d_in[10];
  const float* C2  = (const float*)d_in[11];
  const float* D21 = (const float*)d_in[12];

  char* ws = (char*)d_ws;
  u16*   P     = (u16*)(ws);                  // 8192x896 bf16  = 14,680,064
  u16*   Qt    = (u16*)(ws + 14680064);       // 640x896 bf16   =  1,146,880
  u16*   Rt    = (u16*)(ws + 15826944);       // 256x896 bf16   =    458,752
  float* base2 = (float*)(ws + 16285696);     // 8192x256 f32   =  8,388,608
  float* D11Ts = (float*)(ws + 24674304);     // 256x256 f32    =    262,144
  u16*   Ebf   = (u16*)(ws + 24936448);
  u16*   Y0    = (u16*)(ws + 25460736);
  u16*   Z0    = (u16*)(ws + 25985024);
  u16*   T0T   = (u16*)(ws + 26509312);
  u16*   Y1    = (u16*)(ws + 27033600);
  u16*   McatT = (u16*)(ws + 29130752);       // 896x512 bf16   =    917,504
  float* invLam= (float*)(ws + 30048256);     // 256 f32

  float* dxOut = (float*)d_out;
  float* yOut  = dxOut + (size_t)8192 * 512;

  k_prep<<<4417, 256, 0, stream>>>(C1, D11, D12, Lam, E, F, B1, B2, C2, D21,
                                   Ebf, Y0, Z0, McatT, Qt, Rt, D11Ts, invLam);
  k_convP<<<5120, 256, 0, stream>>>(x, u, P);

  GemmArgs bb{}; bb.A = P; bb.B = Rt; bb.K = 896; bb.outF = base2;
  bb.bv = bv; bb.iLam = invLam;
  gemm_nt<0><<<dim3(2, 64), 256, 0, stream>>>(bb);           // base2 = (x@C1^T+u@D12^T+bv)/lam

  k_solve<<<512, 256, 0, stream>>>(base2, D11Ts, P);         // w -> P[:,512:768] (bf16)

  GemmArgs a{}; a.A = Ebf; a.B = Z0; a.K = 512; a.outBT = T0T;
  gemm_nt<3><<<dim3(4, 4), 256, 0, stream>>>(a);             // T0^T = (E@Y0)^T

  GemmArgs b{}; b.A = Y0; b.B = T0T; b.K = 512; b.outB = Y1; b.ldB = 512;
  b.outBT = nullptr; b.Yprev = Y0;
  gemm_nt<4><<<dim3(4, 4), 256, 0, stream>>>(b);             // Y1 = 2Y0 - Y0@(E@Y0)  (~Einv)

  GemmArgs qq{}; qq.A = Y1; qq.B = McatT; qq.K = 512; qq.outB = Qt; qq.ldB = 896;
  gemm_nt<2><<<dim3(7, 4), 256, 0, stream>>>(qq);            // Qt[0:512] = Einv@[F B1 B2]

  GemmArgs ff{}; ff.A = P; ff.B = Qt; ff.K = 896; ff.dxOut = dxOut; ff.yOut = yOut;
  gemm_nt<1><<<dim3(5, 64), 256, 0, stream>>>(ff);           // [dx | y]
  (void)in_sizes; (void)n_in; (void)out_size; (void)ws_size;
}

// Round 3
// 143.926 us; speedup vs baseline: 2.6522x; 1.1889x over previous
//
#include <hip/hip_runtime.h>

typedef unsigned short u16;
typedef unsigned int   u32;
typedef __attribute__((ext_vector_type(8))) __bf16 bf16x8;
typedef __attribute__((ext_vector_type(4))) float  f32x4;
typedef __attribute__((ext_vector_type(4))) u16    u16x4;

#define DEV __device__ __forceinline__

DEV u16 f2b(float f){ union{float f;u32 u;}a; a.f=f; u32 r=a.u + 0x7FFFu + ((a.u>>16)&1u); return (u16)(r>>16); }
DEV float b2f(u16 h){ union{u32 u;float f;}a; a.u=((u32)h)<<16; return a.f; }

typedef __attribute__((address_space(1))) void* gp1;
typedef __attribute__((address_space(3))) void* lp3;
DEV void gl16(const void* g, void* l){
  __builtin_amdgcn_global_load_lds((gp1)g, (lp3)l, 16, 0, 0);
}

// ---------------------------------------------------------------------------
// fused prep: bf16 conversions, transposed operands, D11^T/lam, invLam, P conv
// ---------------------------------------------------------------------------
__global__ __launch_bounds__(256) void k_prepc(
    const float* __restrict__ x,  const float* __restrict__ u,
    const float* __restrict__ C1, const float* __restrict__ D11,
    const float* __restrict__ D12, const float* __restrict__ Lam,
    const float* __restrict__ E,  const float* __restrict__ F,
    const float* __restrict__ B1, const float* __restrict__ B2,
    const float* __restrict__ C2, const float* __restrict__ D21,
    u16* Ebf, u16* Y0, u16* Z0, u16* McatT, u16* Qt, u16* Rt,
    float* D11Ts, float* invLam, u16* P)
{
  int idx = blockIdx.x * 256 + threadIdx.x;
  if (idx < 262144) {                       // Ebf, Y0 = 2I-E, Z0 = Y0^T
    int i = idx >> 9, j = idx & 511;
    float e = E[idx];
    Ebf[idx] = f2b(e);
    float dij = (i == j) ? 2.f : 0.f;
    Y0[idx] = f2b(dij - e);
    Z0[idx] = f2b(dij - E[j * 512 + i]);
    return;
  }
  idx -= 262144;
  if (idx < 458752) {                       // McatT (896x512) = [F B1 B2]^T
    int j = idx >> 9, c = idx & 511;
    float v = (j < 512) ? F[c * 512 + j]
              : (j < 768 ? B1[c * 256 + (j - 512)] : B2[c * 128 + (j - 768)]);
    McatT[idx] = f2b(v);
    return;
  }
  idx -= 458752;
  if (idx < 114688) {                       // Qt rows 512..639 (y part)
    int j = idx / 896, k = idx - j * 896;
    float v = (k < 512) ? C2[j * 512 + k]
              : (k < 768 ? D21[j * 256 + (k - 512)] : 0.f);
    Qt[(size_t)(512 + j) * 896 + k] = f2b(v);
    return;
  }
  idx -= 114688;
  if (idx < 229376) {                       // Rt (256x896): [C1 | 0 | D12]
    int n = idx / 896, k = idx - n * 896;
    float v = (k < 512) ? C1[n * 512 + k]
              : (k < 768 ? 0.f : D12[n * 128 + (k - 768)]);
    Rt[idx] = f2b(v);
    return;
  }
  idx -= 229376;
  if (idx < 65536) {                        // D11Ts[j][n] = D11[n][j]/lam[n]
    int j = idx >> 8, n = idx & 255;
    D11Ts[idx] = D11[n * 256 + j] / Lam[n * 256 + n];
    return;
  }
  idx -= 65536;
  if (idx < 256) { invLam[idx] = 1.f / Lam[idx * 256 + idx]; return; }
  idx -= 256;
  {                                         // P = [x | . | u] bf16
    int b = idx / 160, t = idx - b * 160;
    f32x4 s; u16* dst;
    if (t < 128) { s = *(const f32x4*)(x + (size_t)b * 512 + t * 4); dst = P + (size_t)b * 896 + t * 4; }
    else         { s = *(const f32x4*)(u + (size_t)b * 128 + (t - 128) * 4); dst = P + (size_t)b * 896 + 768 + (t - 128) * 4; }
    u16x4 o; o.x = f2b(s.x); o.y = f2b(s.y); o.z = f2b(s.z); o.w = f2b(s.w);
    *(u16x4*)dst = o;
  }
}

// ---------------------------------------------------------------------------
// NT bf16 MFMA GEMM, 128x128 tile, BK=32, 256 threads (2x2 waves, 64x64/wave)
// LDS fragment reads 4-way XOR-swizzled (slot = (lk^row)&3), source pre-swz
// ---------------------------------------------------------------------------
struct GemmArgs {
  const u16* A; const u16* B; int K;
  float* outF;                 // EPI 0 (base2, ld=256)
  u16* outB; int ldB;          // EPI 2 bf16
  u16* outBT;                  // EPI 3 transposed bf16 (ld=512)
  const u16* Yprev;            // EPI 4
  const float* bv; const float* iLam;
  float* dxOut; float* yOut;   // EPI 1
};

template<int EPI>
__global__ __launch_bounds__(256) void gemm_nt(GemmArgs g)
{
  __shared__ __align__(16) u16 As[128 * 32];
  __shared__ __align__(16) u16 Bs[128 * 32];
  const int tid = threadIdx.x;
  const int l = tid & 63, w = tid >> 6;
  const int bm = blockIdx.y, bn = blockIdx.x;
  const int K = g.K;
  const size_t rowb = (size_t)K * 2;
  const char* Ab = (const char*)g.A + (size_t)bm * 128 * rowb;
  const char* Bb = (const char*)g.B + (size_t)bn * 128 * rowb;
  const int o1 = w * 1024 + l * 16, o2 = o1 + 4096;
  const int r1 = o1 >> 6, r2 = o2 >> 6;
  const int c1 = (((o1 >> 4) ^ r1) & 3) << 4;   // pre-swizzled source slot
  const int c2 = (((o2 >> 4) ^ r2) & 3) << 4;
  char* AsB = (char*)As; char* BsB = (char*)Bs;
  const int wm = w >> 1, wn = w & 1;
  const int lr = l & 15, lk = l >> 4;
  const int slot = ((lk ^ lr) & 3) << 4;        // swizzled read slot

  f32x4 acc[4][4];
  const f32x4 zz = {0.f, 0.f, 0.f, 0.f};
  #pragma unroll
  for (int i = 0; i < 4; i++)
    #pragma unroll
    for (int j = 0; j < 4; j++) acc[i][j] = zz;

  for (int k0 = 0; k0 < K; k0 += 32) {
    gl16(Ab + (size_t)r1 * rowb + k0 * 2 + c1, AsB + o1);
    gl16(Ab + (size_t)r2 * rowb + k0 * 2 + c2, AsB + o2);
    gl16(Bb + (size_t)r1 * rowb + k0 * 2 + c1, BsB + o1);
    gl16(Bb + (size_t)r2 * rowb + k0 * 2 + c2, BsB + o2);
    __syncthreads();
    bf16x8 af[4], bfv[4];
    #pragma unroll
    for (int mi = 0; mi < 4; mi++)
      af[mi] = *(const bf16x8*)(AsB + (wm * 64 + mi * 16 + lr) * 64 + slot);
    #pragma unroll
    for (int ni = 0; ni < 4; ni++)
      bfv[ni] = *(const bf16x8*)(BsB + (wn * 64 + ni * 16 + lr) * 64 + slot);
    #pragma unroll
    for (int mi = 0; mi < 4; mi++)
      #pragma unroll
      for (int ni = 0; ni < 4; ni++)
        acc[mi][ni] = __builtin_amdgcn_mfma_f32_16x16x32_bf16(af[mi], bfv[ni], acc[mi][ni], 0, 0, 0);
    __syncthreads();
  }

  #pragma unroll
  for (int mi = 0; mi < 4; mi++) {
    #pragma unroll
    for (int ni = 0; ni < 4; ni++) {
      const int row0 = bm * 128 + wm * 64 + mi * 16 + lk * 4;
      const int col  = bn * 128 + wn * 64 + ni * 16 + lr;
      if (EPI == 0) {
        const float bvc = g.bv[col], il = g.iLam[col];
        #pragma unroll
        for (int r = 0; r < 4; r++)
          g.outF[(size_t)(row0 + r) * 256 + col] = (acc[mi][ni][r] + bvc) * il;
      } else if (EPI == 1) {
        #pragma unroll
        for (int r = 0; r < 4; r++) {
          float v = acc[mi][ni][r];
          if (col < 512) g.dxOut[(size_t)(row0 + r) * 512 + col] = v;
          else           g.yOut[(size_t)(row0 + r) * 128 + (col - 512)] = v;
        }
      }
    }
  }
}

// ---------------------------------------------------------------------------
// NT bf16 MFMA GEMM, 64x64 tile for the small 512-wide chain
// 256 thr = 2x2 waves of 32x32
// ---------------------------------------------------------------------------
template<int EPI>
__global__ __launch_bounds__(256) void gemm64(GemmArgs g)
{
  __shared__ __align__(16) u16 As[64 * 32];
  __shared__ __align__(16) u16 Bs[64 * 32];
  const int tid = threadIdx.x;
  const int l = tid & 63, w = tid >> 6;
  const int bm = blockIdx.y, bn = blockIdx.x;
  const int K = g.K;
  const size_t rowb = (size_t)K * 2;
  const char* Ab = (const char*)g.A + (size_t)bm * 64 * rowb;
  const char* Bb = (const char*)g.B + (size_t)bn * 64 * rowb;
  const int o = tid * 16;
  const int r0 = o >> 6;
  const int cs = (((o >> 4) ^ r0) & 3) << 4;
  char* AsB = (char*)As; char* BsB = (char*)Bs;
  const int wm = w >> 1, wn = w & 1;
  const int lr = l & 15, lk = l >> 4;
  const int slot = ((lk ^ lr) & 3) << 4;

  f32x4 acc[2][2];
  const f32x4 zz = {0.f, 0.f, 0.f, 0.f};
  acc[0][0] = zz; acc[0][1] = zz; acc[1][0] = zz; acc[1][1] = zz;

  for (int k0 = 0; k0 < K; k0 += 32) {
    gl16(Ab + (size_t)r0 * rowb + k0 * 2 + cs, AsB + o);
    gl16(Bb + (size_t)r0 * rowb + k0 * 2 + cs, BsB + o);
    __syncthreads();
    bf16x8 af[2], bfv[2];
    #pragma unroll
    for (int mi = 0; mi < 2; mi++)
      af[mi] = *(const bf16x8*)(AsB + (wm * 32 + mi * 16 + lr) * 64 + slot);
    #pragma unroll
    for (int ni = 0; ni < 2; ni++)
      bfv[ni] = *(const bf16x8*)(BsB + (wn * 32 + ni * 16 + lr) * 64 + slot);
    #pragma unroll
    for (int mi = 0; mi < 2; mi++)
      #pragma unroll
      for (int ni = 0; ni < 2; ni++)
        acc[mi][ni] = __builtin_amdgcn_mfma_f32_16x16x32_bf16(af[mi], bfv[ni], acc[mi][ni], 0, 0, 0);
    __syncthreads();
  }

  #pragma unroll
  for (int mi = 0; mi < 2; mi++) {
    #pragma unroll
    for (int ni = 0; ni < 2; ni++) {
      const int row0 = bm * 64 + wm * 32 + mi * 16 + lk * 4;
      const int col  = bn * 64 + wn * 32 + ni * 16 + lr;
      if (EPI == 2) {
        #pragma unroll
        for (int r = 0; r < 4; r++)
          g.outB[(size_t)(row0 + r) * g.ldB + col] = f2b(acc[mi][ni][r]);
      } else if (EPI == 3) {
        #pragma unroll
        for (int r = 0; r < 4; r++)
          g.outBT[(size_t)col * 512 + (row0 + r)] = f2b(acc[mi][ni][r]);
      } else if (EPI == 4) {
        #pragma unroll
        for (int r = 0; r < 4; r++) {
          int row = row0 + r;
          float d = 2.f * b2f(g.Yprev[row * 512 + col]) - acc[mi][ni][r];
          g.outB[(size_t)row * 512 + col] = f2b(d);
        }
      }
    }
  }
}

// ---------------------------------------------------------------------------
// sequential tanh recurrence, right-looking rank-1 updates
// 512 blocks x 256 thr; 16 rows/block, 4 rows/wave; lane c owns col chunks
// {c,16+c,32+c,48+c} (stride-256B LDS reads -> 2-way = free); acc in 4 f32x4;
// D tiles (32x256 f32) double-buffered in LDS; inner 32 steps fully unrolled.
// ---------------------------------------------------------------------------
__global__ __launch_bounds__(256) void k_solve(
    const float* __restrict__ base2, const float* __restrict__ D11Ts,
    u16* __restrict__ P)
{
  __shared__ __align__(16) char Dlds[2][32 * 1024];
  const int tid = threadIdx.x, l = tid & 63, w = tid >> 6;
  const int r = l & 3, c = l >> 2;
  const int row = blockIdx.x * 16 + w * 4 + r;

  const float* brow = base2 + (size_t)row * 256 + c * 4;
  f32x4 aV0 = *(const f32x4*)(brow);
  f32x4 aV1 = *(const f32x4*)(brow + 64);
  f32x4 aV2 = *(const f32x4*)(brow + 128);
  f32x4 aV3 = *(const f32x4*)(brow + 192);

  const char* Dg = (const char*)D11Ts;
  const int d16 = tid * 16;
  #pragma unroll
  for (int s = 0; s < 8; s++)
    gl16(Dg + s * 4096 + d16, Dlds[0] + s * 4096 + d16);
  __syncthreads();

  u16* Prow = P + (size_t)row * 896 + 512;

  for (int kt = 0; kt < 8; kt++) {
    const char* cur = Dlds[kt & 1] + c * 16;
    if (kt < 7) {
      const char* src = Dg + (size_t)(kt + 1) * 32768 + d16;
      char* dst = Dlds[(kt + 1) & 1] + d16;
      #pragma unroll
      for (int s = 0; s < 8; s++)
        gl16(src + s * 4096, dst + s * 4096);
    }
    const int jb = kt >> 1;                       // uniform per tile
    #pragma unroll
    for (int h = 0; h < 2; h++) {
      #pragma unroll
      for (int i = 0; i < 16; i++) {
        const int k2 = h * 16 + i;
        const int k = kt * 32 + k2;
        const int own_c = (k >> 2) & 15;          // uniform scalar
        // v from the statically-indexed acc component (jb select, t static)
        f32x4 gsel = (jb == 0) ? aV0 : (jb == 1) ? aV1 : (jb == 2) ? aV2 : aV3;
        const int t = i & 3;
        float v = (t == 0) ? gsel.x : (t == 1) ? gsel.y : (t == 2) ? gsel.z : gsel.w;
        float e = __expf(2.f * v);
        float wv0 = 1.f - __fdividef(2.f, e + 1.f);
        float wv = __shfl(wv0, own_c * 4 + r, 64);
        if (c == own_c) Prow[k] = f2b(wv);
        const char* dp = cur + k2 * 1024;
        f32x4 d0 = *(const f32x4*)(dp);
        f32x4 d1 = *(const f32x4*)(dp + 256);
        f32x4 d2 = *(const f32x4*)(dp + 512);
        f32x4 d3 = *(const f32x4*)(dp + 768);
        aV0 += wv * d0; aV1 += wv * d1; aV2 += wv * d2; aV3 += wv * d3;
      }
    }
    __syncthreads();
  }
}

// ---------------------------------------------------------------------------
extern "C" void kernel_launch(void* const* d_in, const int* in_sizes, int n_in,
                              void* d_out, int out_size, void* d_ws, size_t ws_size,
                              hipStream_t stream)
{
  const float* x   = (const float*)d_in[0];
  const float* u   = (const float*)d_in[1];
  const float* C1  = (const float*)d_in[2];
  const float* D11 = (const float*)d_in[3];
  const float* D12 = (const float*)d_in[4];
  const float* Lam = (const float*)d_in[5];
  const float* bv  = (const float*)d_in[6];
  const float* E   = (const float*)d_in[7];
  const float* F   = (const float*)d_in[8];
  const float* B1  = (const float*)d_in[9];
  const float* B2  = (const float*)d_in[10];
  const float* C2  = (const float*)d_in[11];
  const float* D21 = (const float*)d_in[12];

  char* ws = (char*)d_ws;
  u16*   P     = (u16*)(ws);                  // 8192x896 bf16  = 14,680,064
  u16*   Qt    = (u16*)(ws + 14680064);       // 640x896 bf16   =  1,146,880
  u16*   Rt    = (u16*)(ws + 15826944);       // 256x896 bf16   =    458,752
  float* base2 = (float*)(ws + 16285696);     // 8192x256 f32   =  8,388,608
  float* D11Ts = (float*)(ws + 24674304);     // 256x256 f32    =    262,144
  u16*   Ebf   = (u16*)(ws + 24936448);
  u16*   Y0    = (u16*)(ws + 25460736);
  u16*   Z0    = (u16*)(ws + 25985024);
  u16*   T0T   = (u16*)(ws + 26509312);
  u16*   Y1    = (u16*)(ws + 27033600);
  u16*   McatT = (u16*)(ws + 29130752);       // 896x512 bf16   =    917,504
  float* invLam= (float*)(ws + 30048256);     // 256 f32

  float* dxOut = (float*)d_out;
  float* yOut  = dxOut + (size_t)8192 * 512;

  k_prepc<<<9537, 256, 0, stream>>>(x, u, C1, D11, D12, Lam, E, F, B1, B2, C2, D21,
                                    Ebf, Y0, Z0, McatT, Qt, Rt, D11Ts, invLam, P);

  GemmArgs bb{}; bb.A = P; bb.B = Rt; bb.K = 896; bb.outF = base2;
  bb.bv = bv; bb.iLam = invLam;
  gemm_nt<0><<<dim3(2, 64), 256, 0, stream>>>(bb);           // base2

  k_solve<<<512, 256, 0, stream>>>(base2, D11Ts, P);         // w -> P[:,512:768]

  GemmArgs a{}; a.A = Ebf; a.B = Z0; a.K = 512; a.outBT = T0T;
  gemm64<3><<<dim3(8, 8), 256, 0, stream>>>(a);              // T0^T = (E@Y0)^T

  GemmArgs b{}; b.A = Y0; b.B = T0T; b.K = 512; b.outB = Y1; b.ldB = 512;
  b.Yprev = Y0;
  gemm64<4><<<dim3(8, 8), 256, 0, stream>>>(b);              // Y1 = 2Y0 - Y0@(E@Y0)

  GemmArgs qq{}; qq.A = Y1; qq.B = McatT; qq.K = 512; qq.outB = Qt; qq.ldB = 896;
  gemm64<2><<<dim3(14, 8), 256, 0, stream>>>(qq);            // Qt[0:512] = Einv@[F B1 B2]

  GemmArgs ff{}; ff.A = P; ff.B = Qt; ff.K = 896; ff.dxOut = dxOut; ff.yOut = yOut;
  gemm_nt<1><<<dim3(5, 64), 256, 0, stream>>>(ff);           // [dx | y]
  (void)in_sizes; (void)n_in; (void)out_size; (void)ws_size;
}